// Round 1
// baseline (143.058 us; speedup 1.0000x reference)
//
#include <hip/hip_runtime.h>

#define D_DIM 512

// ---- per-row entropy-ish sums: E[row] = sum_d x * log2(x)  (one wave per row)
__global__ void jsd_entropy_kernel(const float* __restrict__ a,
                                   const float* __restrict__ b,
                                   float* __restrict__ E, int N, int M) {
    int row = blockIdx.x;
    const float* src = (row < N) ? (a + (size_t)row * D_DIM)
                                 : (b + (size_t)(row - N) * D_DIM);
    int lane = threadIdx.x;  // 0..63, one wave
    float s = 0.f;
    for (int d = lane; d < D_DIM; d += 64) {
        float x = src[d];
        s = fmaf(x, __log2f(x), s);
    }
#pragma unroll
    for (int off = 32; off > 0; off >>= 1) s += __shfl_down(s, off, 64);
    if (lane == 0) E[row] = s;
}

// ---- main pairwise kernel: out[i,j] = 1 - 0.5*S_ij + 0.5*(Ea[i] + Eb[j])
//      S_ij = sum_d (a_id + b_jd) * log2(a_id + b_jd)
constexpr int BN = 64;   // a-rows per block
constexpr int BM = 64;   // b-rows per block
constexpr int DK = 32;   // d-chunk in LDS
constexpr int RP = 68;   // padded row length ([d][row] layout); 68*4B=272B keeps
                         // 16B alignment for b128 and breaks bank aliasing

__global__ __launch_bounds__(256)
void jsd_main_kernel(const float* __restrict__ a, const float* __restrict__ b,
                     const float* __restrict__ Ea, const float* __restrict__ Eb,
                     float* __restrict__ out, int N, int M) {
    __shared__ float As[DK][RP];  // As[d][row]  (transposed staging)
    __shared__ float Bs[DK][RP];

    const int tid = threadIdx.x;      // 256 threads
    const int tx = tid & 15;          // b-col group
    const int ty = tid >> 4;          // a-row group
    const int rowBase = blockIdx.y * BN;
    const int colBase = blockIdx.x * BM;

    float acc[4][4] = {};

    for (int dBase = 0; dBase < D_DIM; dBase += DK) {
        // ---- stage: coalesced float4 global loads, transposed scalar LDS writes
#pragma unroll
        for (int rep = 0; rep < 2; ++rep) {
            int idx = tid + rep * 256;   // 0..511
            int r = idx >> 3;            // 0..63 (tile row)
            int q = idx & 7;             // 0..7  (float4 index within 32-d chunk)
            const float4 va = *(const float4*)(a + (size_t)(rowBase + r) * D_DIM + dBase + 4 * q);
            const float4 vb = *(const float4*)(b + (size_t)(colBase + r) * D_DIM + dBase + 4 * q);
            As[4 * q + 0][r] = va.x; As[4 * q + 1][r] = va.y;
            As[4 * q + 2][r] = va.z; As[4 * q + 3][r] = va.w;
            Bs[4 * q + 0][r] = vb.x; Bs[4 * q + 1][r] = vb.y;
            Bs[4 * q + 2][r] = vb.z; Bs[4 * q + 3][r] = vb.w;
        }
        __syncthreads();

#pragma unroll 4
        for (int dk = 0; dk < DK; ++dk) {
            float4 av = *(const float4*)&As[dk][ty * 4];  // 4 consecutive rows
            float4 bv = *(const float4*)&Bs[dk][tx * 4];  // 4 consecutive cols
            float ar[4] = {av.x, av.y, av.z, av.w};
            float br[4] = {bv.x, bv.y, bv.z, bv.w};
#pragma unroll
            for (int r = 0; r < 4; ++r)
#pragma unroll
                for (int c = 0; c < 4; ++c) {
                    float t = ar[r] + br[c];
                    acc[r][c] = fmaf(t, __log2f(t), acc[r][c]);
                }
        }
        __syncthreads();
    }

    // ---- epilogue
#pragma unroll
    for (int r = 0; r < 4; ++r) {
        int i = rowBase + ty * 4 + r;
        float ea = Ea[i];
#pragma unroll
        for (int c = 0; c < 4; ++c) {
            int j = colBase + tx * 4 + c;
            out[(size_t)i * M + j] = 1.0f - 0.5f * acc[r][c] + 0.5f * (ea + Eb[j]);
        }
    }
}

extern "C" void kernel_launch(void* const* d_in, const int* in_sizes, int n_in,
                              void* d_out, int out_size, void* d_ws, size_t ws_size,
                              hipStream_t stream) {
    const float* a = (const float*)d_in[0];
    const float* b = (const float*)d_in[1];
    const int N = in_sizes[0] / D_DIM;   // 1024
    const int M = in_sizes[1] / D_DIM;   // 1024
    float* E = (float*)d_ws;             // Ea[0..N), Eb[N..N+M)

    jsd_entropy_kernel<<<N + M, 64, 0, stream>>>(a, b, E, N, M);

    dim3 grid(M / BM, N / BN);           // 16 x 16 = 256 blocks
    jsd_main_kernel<<<grid, 256, 0, stream>>>(a, b, E, E + N, (float*)d_out, N, M);
}

// Round 2
// 116.620 us; speedup vs baseline: 1.2267x; 1.2267x over previous
//
#include <hip/hip_runtime.h>

#define D_DIM 512

__device__ __forceinline__ float flog2(float x) {
    return __builtin_amdgcn_logf(x);   // bare v_log_f32 (no OCML denormal wrapper)
}

// ---- per-row sums: E[row] = sum_d x*log2(x). One wave per row, 4 rows/block.
__global__ __launch_bounds__(256)
void jsd_entropy_kernel(const float* __restrict__ a,
                        const float* __restrict__ b,
                        float* __restrict__ E, int N, int M) {
    int wave = threadIdx.x >> 6;
    int lane = threadIdx.x & 63;
    int row = blockIdx.x * 4 + wave;
    if (row >= N + M) return;
    const float* src = (row < N) ? (a + (size_t)row * D_DIM)
                                 : (b + (size_t)(row - N) * D_DIM);
    float s = 0.f;
#pragma unroll
    for (int d = lane; d < D_DIM; d += 64) {
        float x = src[d];
        s = fmaf(x, flog2(x), s);
    }
#pragma unroll
    for (int off = 32; off > 0; off >>= 1) s += __shfl_down(s, off, 64);
    if (lane == 0) E[row] = s;
}

// ---- main: out[i,j] = 1 - 0.5*S_ij + 0.5*(Ea[i] + Eb[j])
//      S_ij = sum_d t*log2(t), t = a_id + b_jd
constexpr int BN = 32;   // a-rows per block
constexpr int BM = 32;   // b-cols per block
constexpr int DK = 32;   // d-chunk in LDS
constexpr int RP = 34;   // row pad: 34 floats = 136 B -> b64-aligned reads,
                         // staging writes land 2-way on banks (free, m136)

__global__ __launch_bounds__(256)
void jsd_main_kernel(const float* __restrict__ a, const float* __restrict__ b,
                     const float* __restrict__ Ea, const float* __restrict__ Eb,
                     float* __restrict__ out, int N, int M) {
    __shared__ float As[DK][RP];  // [d][row] transposed staging
    __shared__ float Bs[DK][RP];

    const int tid = threadIdx.x;       // 256 threads = 16x16
    const int tx = tid & 15;           // col group (x2)
    const int ty = tid >> 4;           // row group (x2)
    const int rowBase = blockIdx.y * BN;
    const int colBase = blockIdx.x * BM;

    float acc[2][2] = {};

    for (int dBase = 0; dBase < D_DIM; dBase += DK) {
        // stage 32 rows x 32 d of each of A,B: 256 float4s each, 1 per thread
        {
            int r = tid >> 3;          // 0..31
            int q = tid & 7;           // float4 index in 32-d chunk
            const float4 va = *(const float4*)(a + (size_t)(rowBase + r) * D_DIM + dBase + 4 * q);
            const float4 vb = *(const float4*)(b + (size_t)(colBase + r) * D_DIM + dBase + 4 * q);
            As[4 * q + 0][r] = va.x; As[4 * q + 1][r] = va.y;
            As[4 * q + 2][r] = va.z; As[4 * q + 3][r] = va.w;
            Bs[4 * q + 0][r] = vb.x; Bs[4 * q + 1][r] = vb.y;
            Bs[4 * q + 2][r] = vb.z; Bs[4 * q + 3][r] = vb.w;
        }
        __syncthreads();

#pragma unroll 8
        for (int dk = 0; dk < DK; ++dk) {
            float2 av = *(const float2*)&As[dk][ty * 2];
            float2 bv = *(const float2*)&Bs[dk][tx * 2];
            float ar[2] = {av.x, av.y};
            float br[2] = {bv.x, bv.y};
#pragma unroll
            for (int r = 0; r < 2; ++r)
#pragma unroll
                for (int c = 0; c < 2; ++c) {
                    float t = ar[r] + br[c];
                    acc[r][c] = fmaf(t, flog2(t), acc[r][c]);
                }
        }
        __syncthreads();
    }

    // epilogue: float2 stores, lanes tx consecutive -> coalesced 128B/row-group
    const float eb0 = Eb[colBase + tx * 2 + 0];
    const float eb1 = Eb[colBase + tx * 2 + 1];
#pragma unroll
    for (int r = 0; r < 2; ++r) {
        int i = rowBase + ty * 2 + r;
        float ea = Ea[i];
        float2 res;
        res.x = 1.0f - 0.5f * acc[r][0] + 0.5f * (ea + eb0);
        res.y = 1.0f - 0.5f * acc[r][1] + 0.5f * (ea + eb1);
        *(float2*)(out + (size_t)i * M + colBase + tx * 2) = res;
    }
}

extern "C" void kernel_launch(void* const* d_in, const int* in_sizes, int n_in,
                              void* d_out, int out_size, void* d_ws, size_t ws_size,
                              hipStream_t stream) {
    const float* a = (const float*)d_in[0];
    const float* b = (const float*)d_in[1];
    const int N = in_sizes[0] / D_DIM;   // 1024
    const int M = in_sizes[1] / D_DIM;   // 1024
    float* E = (float*)d_ws;             // Ea[0..N), Eb[N..N+M)

    jsd_entropy_kernel<<<(N + M + 3) / 4, 256, 0, stream>>>(a, b, E, N, M);

    dim3 grid(M / BM, N / BN);           // 32 x 32 = 1024 blocks
    jsd_main_kernel<<<grid, 256, 0, stream>>>(a, b, E, E + N, (float*)d_out, N, M);
}

// Round 3
// 114.435 us; speedup vs baseline: 1.2501x; 1.0191x over previous
//
#include <hip/hip_runtime.h>

#define D_DIM 512

__device__ __forceinline__ float flog2(float x) {
    return __builtin_amdgcn_logf(x);   // bare v_log_f32 (inputs >= ~2e-6, no denormal wrapper needed)
}

// ---- per-row sums: E[row] = sum_d x*log2(x). One wave per row, 4 rows/block.
__global__ __launch_bounds__(256)
void jsd_entropy_kernel(const float* __restrict__ a,
                        const float* __restrict__ b,
                        float* __restrict__ E, int N, int M) {
    int wave = threadIdx.x >> 6;
    int lane = threadIdx.x & 63;
    int row = blockIdx.x * 4 + wave;
    if (row >= N + M) return;
    const float* src = (row < N) ? (a + (size_t)row * D_DIM)
                                 : (b + (size_t)(row - N) * D_DIM);
    float s = 0.f;
#pragma unroll
    for (int d = lane; d < D_DIM; d += 64) {
        float x = src[d];
        s = fmaf(x, flog2(x), s);
    }
#pragma unroll
    for (int off = 32; off > 0; off >>= 1) s += __shfl_down(s, off, 64);
    if (lane == 0) E[row] = s;
}

// ---- main: out[i,j] = 1 - 0.5*S_ij + 0.5*(Ea[i] + Eb[j]),  S_ij = sum_d t*log2(t)
// Split-D x2: grid (32,32,2) = 2048 blocks -> 8 blocks/CU (32 waves/CU).
// Each z-half atomically adds its partial; z==0 also adds the affine term.
constexpr int BN = 32, BM = 32;
constexpr int DK = 64;       // d per LDS staging chunk
constexpr int DSPLIT = 256;  // d per block
constexpr int RP = 34;       // row pad: b64-aligned reads, 2-way bank alias (free)

__global__ __launch_bounds__(256)
void jsd_main_kernel(const float* __restrict__ a, const float* __restrict__ b,
                     const float* __restrict__ Ea, const float* __restrict__ Eb,
                     float* __restrict__ out, int N, int M) {
    __shared__ float As[DK][RP];  // [d][row] transposed staging
    __shared__ float Bs[DK][RP];

    const int tid = threadIdx.x;       // 256 threads = 16x16
    const int tx = tid & 15;           // col group (x2)
    const int ty = tid >> 4;           // row group (x2)
    const int rowBase = blockIdx.y * BN;
    const int colBase = blockIdx.x * BM;
    const int dStart  = blockIdx.z * DSPLIT;

    float acc[2][2] = {};

    for (int dBase = dStart; dBase < dStart + DSPLIT; dBase += DK) {
        // stage 32 rows x 64 d of each of A,B: 512 float4s each -> 2 per thread
#pragma unroll
        for (int rep = 0; rep < 2; ++rep) {
            int idx = tid + rep * 256;   // 0..511
            int r = idx >> 4;            // 0..31 (tile row)
            int q = idx & 15;            // 0..15 (float4 index in 64-d chunk)
            const float4 va = *(const float4*)(a + (size_t)(rowBase + r) * D_DIM + dBase + 4 * q);
            const float4 vb = *(const float4*)(b + (size_t)(colBase + r) * D_DIM + dBase + 4 * q);
            As[4 * q + 0][r] = va.x; As[4 * q + 1][r] = va.y;
            As[4 * q + 2][r] = va.z; As[4 * q + 3][r] = va.w;
            Bs[4 * q + 0][r] = vb.x; Bs[4 * q + 1][r] = vb.y;
            Bs[4 * q + 2][r] = vb.z; Bs[4 * q + 3][r] = vb.w;
        }
        __syncthreads();

#pragma unroll 8
        for (int dk = 0; dk < DK; ++dk) {
            float2 av = *(const float2*)&As[dk][ty * 2];
            float2 bv = *(const float2*)&Bs[dk][tx * 2];
            float ar[2] = {av.x, av.y};
            float br[2] = {bv.x, bv.y};
#pragma unroll
            for (int r = 0; r < 2; ++r)
#pragma unroll
                for (int c = 0; c < 2; ++c) {
                    float t = ar[r] + br[c];
                    acc[r][c] = fmaf(t, flog2(t), acc[r][c]);
                }
        }
        __syncthreads();
    }

    // epilogue: z==0 folds the affine term; both halves atomicAdd their partial
    const bool lead = (blockIdx.z == 0);
    const float eb0 = lead ? Eb[colBase + tx * 2 + 0] : 0.f;
    const float eb1 = lead ? Eb[colBase + tx * 2 + 1] : 0.f;
#pragma unroll
    for (int r = 0; r < 2; ++r) {
        int i = rowBase + ty * 2 + r;
        float ea = lead ? Ea[i] : 0.f;
        float v0 = -0.5f * acc[r][0] + (lead ? 1.0f + 0.5f * (ea + eb0) : 0.0f);
        float v1 = -0.5f * acc[r][1] + (lead ? 1.0f + 0.5f * (ea + eb1) : 0.0f);
        float* p = out + (size_t)i * M + colBase + tx * 2;
        atomicAdd(p + 0, v0);
        atomicAdd(p + 1, v1);
    }
}

extern "C" void kernel_launch(void* const* d_in, const int* in_sizes, int n_in,
                              void* d_out, int out_size, void* d_ws, size_t ws_size,
                              hipStream_t stream) {
    const float* a = (const float*)d_in[0];
    const float* b = (const float*)d_in[1];
    const int N = in_sizes[0] / D_DIM;   // 1024
    const int M = in_sizes[1] / D_DIM;   // 1024
    float* E = (float*)d_ws;             // Ea[0..N), Eb[N..N+M)

    hipMemsetAsync(d_out, 0, (size_t)out_size * sizeof(float), stream);
    jsd_entropy_kernel<<<(N + M + 3) / 4, 256, 0, stream>>>(a, b, E, N, M);

    dim3 grid(M / BM, N / BN, D_DIM / DSPLIT);   // 32 x 32 x 2 = 2048 blocks
    jsd_main_kernel<<<grid, 256, 0, stream>>>(a, b, E, E + N, (float*)d_out, N, M);
}